// Round 9
// baseline (209.810 us; speedup 1.0000x reference)
//
#include <hip/hip_runtime.h>
#include <hip/hip_bf16.h>
#include <hip/hip_fp16.h>
#include <stdint.h>

#define NNODES 100000
#define HID 128
#define NEDGES 1000000
#define NEBLOCKS 15625  // edge blocks: 15625 * 4 waves * 16 edges = 1,000,000

typedef __attribute__((ext_vector_type(8))) short short8;
typedef __attribute__((ext_vector_type(4))) float floatx4;
typedef _Float16 f16x2 __attribute__((ext_vector_type(2)));
typedef _Float16 f16x8 __attribute__((ext_vector_type(8)));

// ---------------- Kernel 0: pack B = [W1_top | W1_bot] into MFMA fragment
// order, f16. Fragment: B[k=(lane>>4)*8+j][n=lane&15],
// element base ((ct*4+ks)*64+lane)*8, ct=0..15 (16-col tiles), ks=0..3.
__global__ __launch_bounds__(256) void pack_b_kernel(
    const float* __restrict__ W1, _Float16* __restrict__ Bf) {
  const int t = blockIdx.x * 256 + threadIdx.x;  // 0..4095
  const int lane = t & 63;
  const int ks = (t >> 6) & 3;
  const int ct = t >> 8;
  const int n = ct * 16 + (lane & 15);
  const int kb = ks * 32 + ((lane >> 4) * 8);
  f16x8 h;
#pragma unroll
  for (int j = 0; j < 8; ++j) {
    const int k = kb + j;
    const float v = (n < HID) ? W1[(size_t)k * HID + n]
                              : W1[(size_t)(HID + k) * HID + (n - HID)];
    h[j] = (_Float16)v;
  }
  *(f16x8*)(Bf + (size_t)t * 8) = h;
}

// ---------------- Kernel 1: node projection via single-pass f16 MFMA -------
// Block: 64 rows x 256 cols. A fragments loaded directly from emb as fp32
// (2 dwordx4 per fragment), converted to f16 in-register. 64 MFMA/wave.
// P[m][n] fp16 store via LDS epilogue.
__global__ __launch_bounds__(256) void project_kernel(
    const float* __restrict__ emb, const _Float16* __restrict__ Bf,
    __half* __restrict__ P) {
  __shared__ __half Co[64 * 264];  // 33792 B

  const int t = threadIdx.x;
  const int lane = t & 63;
  const int w = t >> 6;
  const int l16 = lane & 15;
  const int q = lane >> 4;
  const int row0 = blockIdx.x * 64;

  floatx4 acc[4][4] = {};  // [rt][ct]

  // per-lane A row (clamped so tail-block loads stay in-bounds; those rows
  // produce garbage accs that the epilogue never stores)
  int arow[4];
#pragma unroll
  for (int rt = 0; rt < 4; ++rt) {
    int r = row0 + rt * 16 + l16;
    arow[rt] = (r < NNODES) ? r : (NNODES - 1);
  }

#pragma unroll
  for (int ks = 0; ks < 4; ++ks) {
    f16x8 bh[4];
#pragma unroll
    for (int ct = 0; ct < 4; ++ct) {
      const size_t idx = (size_t)(((w * 4 + ct) * 4 + ks) * 64 + lane) * 8;
      bh[ct] = *(const f16x8*)(Bf + idx);
    }
    floatx4 a0[4], a1[4];
#pragma unroll
    for (int rt = 0; rt < 4; ++rt) {
      const float* ap = emb + (size_t)arow[rt] * HID + ks * 32 + q * 8;
      a0[rt] = *(const floatx4*)ap;
      a1[rt] = *(const floatx4*)(ap + 4);
    }
#pragma unroll
    for (int rt = 0; rt < 4; ++rt) {
      f16x8 ah;
      ah[0] = (_Float16)a0[rt].x; ah[1] = (_Float16)a0[rt].y;
      ah[2] = (_Float16)a0[rt].z; ah[3] = (_Float16)a0[rt].w;
      ah[4] = (_Float16)a1[rt].x; ah[5] = (_Float16)a1[rt].y;
      ah[6] = (_Float16)a1[rt].z; ah[7] = (_Float16)a1[rt].w;
#pragma unroll
      for (int ct = 0; ct < 4; ++ct) {
        acc[rt][ct] = __builtin_amdgcn_mfma_f32_16x16x32_f16(ah, bh[ct], acc[rt][ct], 0, 0, 0);
      }
    }
  }

  // epilogue: C/D layout col=lane&15, row=(lane>>4)*4+reg -> LDS -> coalesced.
#pragma unroll
  for (int rt = 0; rt < 4; ++rt)
#pragma unroll
    for (int ct = 0; ct < 4; ++ct)
#pragma unroll
      for (int r = 0; r < 4; ++r) {
        const int row = rt * 16 + q * 4 + r;
        const int col = w * 64 + ct * 16 + l16;
        Co[row * 264 + col] = __float2half(acc[rt][ct][r]);
      }
  __syncthreads();
#pragma unroll
  for (int i = 0; i < 8; ++i) {
    const int chunk = t + i * 256;  // 2048 chunks of 16B, 32 per row
    const int row = chunk >> 5;
    const int cx = chunk & 31;
    if (row0 + row < NNODES) {
      const floatx4 v = *(const floatx4*)&Co[row * 264 + cx * 8];
      *(floatx4*)(P + (size_t)(row0 + row) * 256 + cx * 8) = v;
    }
  }
}

// ---------------- Kernel 2: per-edge MLP + exp --------------------
// Exact-fit grid: 15625 blocks x 4 waves x 16 edges = 1,000,000. No loop,
// no bounds checks. 16 lanes/edge, 8 halfs/lane (dwordx4 gathers),
// packed-half math + v_dot2_f32_f16, 4-shuffle reduce per 4 edges.
// Block partial sum -> plain store to partials[blockIdx.x] (no atomics).
__global__ __launch_bounds__(256) void edge_kernel(
    const __half* __restrict__ P, const int* __restrict__ lm,
    const float* __restrict__ b1, const float* __restrict__ W2,
    const float* __restrict__ b2, float* __restrict__ explog,
    float* __restrict__ partials) {
  const int lane = threadIdx.x & 63;
  const int wid = threadIdx.x >> 6;
  const int g = lane >> 4;    // edge sub-group 0..3
  const int l16 = lane & 15;
  const int c = l16 * 8;      // 8 halfs per lane

  f16x2 b1h[4], w2h[4];
  {
    const floatx4 b1a = *(const floatx4*)(b1 + c);
    const floatx4 b1b = *(const floatx4*)(b1 + c + 4);
    const floatx4 w2a = *(const floatx4*)(W2 + c);
    const floatx4 w2b = *(const floatx4*)(W2 + c + 4);
    b1h[0] = f16x2{(_Float16)b1a.x, (_Float16)b1a.y};
    b1h[1] = f16x2{(_Float16)b1a.z, (_Float16)b1a.w};
    b1h[2] = f16x2{(_Float16)b1b.x, (_Float16)b1b.y};
    b1h[3] = f16x2{(_Float16)b1b.z, (_Float16)b1b.w};
    w2h[0] = f16x2{(_Float16)w2a.x, (_Float16)w2a.y};
    w2h[1] = f16x2{(_Float16)w2a.z, (_Float16)w2a.w};
    w2h[2] = f16x2{(_Float16)w2b.x, (_Float16)w2b.y};
    w2h[3] = f16x2{(_Float16)w2b.z, (_Float16)w2b.w};
  }
  const f16x2 z2 = {(_Float16)0.f, (_Float16)0.f};
  const float b2v = b2[0];

  const int e0 = (blockIdx.x * 4 + wid) * 16;

  uint4 rs[4], rt_[4];
#pragma unroll
  for (int j = 0; j < 4; ++j) {
    const int ej = e0 + j * 4 + g;
    const int src = lm[ej];
    const int tgt = lm[NEDGES + ej];
    rs[j]  = *(const uint4*)(P + (size_t)src * 256 + c);
    rt_[j] = *(const uint4*)(P + (size_t)tgt * 256 + 128 + c);
  }
  float lsum = 0.f;
#pragma unroll
  for (int j = 0; j < 4; ++j) {
    float p = 0.f;
    const unsigned su[4] = {rs[j].x, rs[j].y, rs[j].z, rs[j].w};
    const unsigned tu[4] = {rt_[j].x, rt_[j].y, rt_[j].z, rt_[j].w};
#pragma unroll
    for (int h = 0; h < 4; ++h) {
      const f16x2 s = __builtin_bit_cast(f16x2, su[h]);
      const f16x2 tt = __builtin_bit_cast(f16x2, tu[h]);
      const f16x2 a = __builtin_elementwise_max(s + tt + b1h[h], z2);
      p = __builtin_amdgcn_fdot2(a, w2h[h], p, false);
    }
    p += __shfl_xor(p, 8, 64);
    p += __shfl_xor(p, 4, 64);
    p += __shfl_xor(p, 2, 64);
    p += __shfl_xor(p, 1, 64);
    if (l16 == j) {
      const float ev = __expf(p + b2v);
      explog[e0 + j * 4 + g] = ev;
      lsum += ev;
    }
  }

#pragma unroll
  for (int off = 32; off >= 1; off >>= 1) lsum += __shfl_xor(lsum, off, 64);
  __shared__ float wsums[4];
  if (lane == 0) wsums[wid] = lsum;
  __syncthreads();
  if (threadIdx.x == 0)
    partials[blockIdx.x] = wsums[0] + wsums[1] + wsums[2] + wsums[3];
}

// ---------------- Kernel 2.5: reduce partials -> accum (single block) ------
__global__ __launch_bounds__(256) void reduce_kernel(
    const float* __restrict__ partials, float* __restrict__ accum) {
  float s = 0.f;
  for (int i = threadIdx.x; i < NEBLOCKS; i += 256) s += partials[i];
#pragma unroll
  for (int off = 32; off >= 1; off >>= 1) s += __shfl_xor(s, off, 64);
  __shared__ float ws_[4];
  if ((threadIdx.x & 63) == 0) ws_[threadIdx.x >> 6] = s;
  __syncthreads();
  if (threadIdx.x == 0) accum[0] = ws_[0] + ws_[1] + ws_[2] + ws_[3];
}

// ---------------- Kernel 3: normalize ----------------
__global__ __launch_bounds__(256) void norm_kernel(
    const float* __restrict__ explog, const float* __restrict__ sum_accum,
    float* __restrict__ out) {
  const float inv = 1.0f / *sum_accum;
  const int i = (blockIdx.x * 256 + threadIdx.x) * 4;
  if (i < NEDGES) {
    floatx4 v = *(const floatx4*)(explog + i);
    v.x *= inv; v.y *= inv; v.z *= inv; v.w *= inv;
    *(floatx4*)(out + i) = v;
  }
}

extern "C" void kernel_launch(void* const* d_in, const int* in_sizes, int n_in,
                              void* d_out, int out_size, void* d_ws, size_t ws_size,
                              hipStream_t stream) {
  const float* emb = (const float*)d_in[0];
  const int*   lm  = (const int*)d_in[1];   // [2, 1M]: sources then targets
  const float* W1  = (const float*)d_in[2];
  const float* b1  = (const float*)d_in[3];
  const float* W2  = (const float*)d_in[4];
  const float* b2  = (const float*)d_in[5];
  float* out = (float*)d_out;

  char* ws = (char*)d_ws;
  __half* P       = (__half*)ws;                   // 51,200,000 B
  float* accum    = (float*)(ws + 51200000);       // 256 B
  float* explog   = (float*)(ws + 51200256);       // 4,000,000 B
  _Float16* Bf    = (_Float16*)(ws + 55200256);    // 65,536 B
  float* partials = (float*)(ws + 55265792);       // 15625*4 B

  pack_b_kernel<<<16, 256, 0, stream>>>(W1, Bf);
  project_kernel<<<1563, 256, 0, stream>>>(emb, Bf, P);
  edge_kernel<<<NEBLOCKS, 256, 0, stream>>>(P, lm, b1, W2, b2, explog, partials);
  reduce_kernel<<<1, 256, 0, stream>>>(partials, accum);
  norm_kernel<<<977, 256, 0, stream>>>(explog, accum, out);
}

// Round 10
// 184.366 us; speedup vs baseline: 1.1380x; 1.1380x over previous
//
#include <hip/hip_runtime.h>
#include <hip/hip_bf16.h>
#include <hip/hip_fp16.h>
#include <stdint.h>

#define NNODES 100000
#define HID 128
#define NEDGES 1000000
#define NEBLOCKS 15625  // edge blocks: 15625 * 4 waves * 16 edges = 1,000,000

typedef __attribute__((ext_vector_type(8))) short short8;
typedef __attribute__((ext_vector_type(4))) float floatx4;
typedef _Float16 f16x2 __attribute__((ext_vector_type(2)));
typedef _Float16 f16x4 __attribute__((ext_vector_type(4)));
typedef _Float16 f16x8 __attribute__((ext_vector_type(8)));

// ---------------- Kernel 0: pack B = [W1_top | W1_bot] into MFMA fragment
// order, f16. Fragment: B[k=(lane>>4)*8+j][n=lane&15],
// element base ((ct*4+ks)*64+lane)*8, ct=0..15 (16-col tiles), ks=0..3.
__global__ __launch_bounds__(256) void pack_b_kernel(
    const float* __restrict__ W1, _Float16* __restrict__ Bf) {
  const int t = blockIdx.x * 256 + threadIdx.x;  // 0..4095
  const int lane = t & 63;
  const int ks = (t >> 6) & 3;
  const int ct = t >> 8;
  const int n = ct * 16 + (lane & 15);
  const int kb = ks * 32 + ((lane >> 4) * 8);
  f16x8 h;
#pragma unroll
  for (int j = 0; j < 8; ++j) {
    const int k = kb + j;
    const float v = (n < HID) ? W1[(size_t)k * HID + n]
                              : W1[(size_t)(HID + k) * HID + (n - HID)];
    h[j] = (_Float16)v;
  }
  *(f16x8*)(Bf + (size_t)t * 8) = h;
}

// ---------------- Kernel 1: node projection via single-pass f16 MFMA -------
// Block: 64 rows x 256 cols. Staging: fully-coalesced flat copy (each wave
// reads contiguous 1KB per instr), in-register fp32->f16, LDS As[row][k]
// stride 136 halfs. One barrier, then K-loop: A via ds_read_b128, B frags
// from L2-hot packed global, 64 MFMA/wave. Co aliases As for the epilogue.
__global__ __launch_bounds__(256) void project_kernel(
    const float* __restrict__ emb, const _Float16* __restrict__ Bf,
    __half* __restrict__ P) {
  __shared__ __align__(16) char smem[64 * 264 * 2];  // 33792 B
  _Float16* As = (_Float16*)smem;  // [row][k], stride 136 halfs (17408 B used)
  __half* Co = (__half*)smem;      // alias after K-loop, 64 x 264

  const int t = threadIdx.x;
  const int lane = t & 63;
  const int w = t >> 6;
  const int l16 = lane & 15;
  const int q = lane >> 4;
  const int row0 = blockIdx.x * 64;

  // ---- staging: load i covers flat float idx t*4 + i*1024 (wave-contiguous)
  // row = (t>>5) + i*8, col = (t&31)*4. Clamp row for the tail block.
  {
    const int r_base = t >> 5;       // 0..7
    const int col = (t & 31) * 4;    // 0..124
#pragma unroll
    for (int i = 0; i < 8; ++i) {
      int grow = row0 + r_base + i * 8;
      if (grow >= NNODES) grow = NNODES - 1;
      const floatx4 v = *(const floatx4*)(emb + (size_t)grow * HID + col);
      f16x4 h;
      h[0] = (_Float16)v.x; h[1] = (_Float16)v.y;
      h[2] = (_Float16)v.z; h[3] = (_Float16)v.w;
      *(f16x4*)&As[(r_base + i * 8) * 136 + col] = h;
    }
  }
  __syncthreads();

  floatx4 acc[4][4] = {};  // [rt][ct]
#pragma unroll
  for (int ks = 0; ks < 4; ++ks) {
    f16x8 bh[4];
#pragma unroll
    for (int ct = 0; ct < 4; ++ct) {
      const size_t idx = (size_t)(((w * 4 + ct) * 4 + ks) * 64 + lane) * 8;
      bh[ct] = *(const f16x8*)(Bf + idx);
    }
    f16x8 ah[4];
#pragma unroll
    for (int rt = 0; rt < 4; ++rt)
      ah[rt] = *(const f16x8*)&As[(rt * 16 + l16) * 136 + ks * 32 + q * 8];
#pragma unroll
    for (int rt = 0; rt < 4; ++rt)
#pragma unroll
      for (int ct = 0; ct < 4; ++ct)
        acc[rt][ct] = __builtin_amdgcn_mfma_f32_16x16x32_f16(ah[rt], bh[ct], acc[rt][ct], 0, 0, 0);
  }

  // epilogue: C/D layout col=lane&15, row=(lane>>4)*4+reg -> LDS -> coalesced.
  __syncthreads();  // As reads done; safe to alias Co
#pragma unroll
  for (int rt = 0; rt < 4; ++rt)
#pragma unroll
    for (int ct = 0; ct < 4; ++ct)
#pragma unroll
      for (int r = 0; r < 4; ++r) {
        const int row = rt * 16 + q * 4 + r;
        const int col = w * 64 + ct * 16 + l16;
        Co[row * 264 + col] = __float2half(acc[rt][ct][r]);
      }
  __syncthreads();
#pragma unroll
  for (int i = 0; i < 8; ++i) {
    const int chunk = t + i * 256;  // 2048 chunks of 16B, 32 per row
    const int row = chunk >> 5;
    const int cx = chunk & 31;
    if (row0 + row < NNODES) {
      const floatx4 v = *(const floatx4*)&Co[row * 264 + cx * 8];
      *(floatx4*)(P + (size_t)(row0 + row) * 256 + cx * 8) = v;
    }
  }
}

// ---------------- Kernel 2: per-edge MLP + exp --------------------
// Exact-fit grid: 15625 blocks x 4 waves x 16 edges = 1,000,000. No loop,
// no bounds checks. 16 lanes/edge, 8 halfs/lane (dwordx4 gathers),
// packed-half math + v_dot2_f32_f16, 4-shuffle reduce per 4 edges.
// Block partial sum -> plain store to partials[blockIdx.x] (no atomics).
__global__ __launch_bounds__(256) void edge_kernel(
    const __half* __restrict__ P, const int* __restrict__ lm,
    const float* __restrict__ b1, const float* __restrict__ W2,
    const float* __restrict__ b2, float* __restrict__ explog,
    float* __restrict__ partials) {
  const int lane = threadIdx.x & 63;
  const int wid = threadIdx.x >> 6;
  const int g = lane >> 4;    // edge sub-group 0..3
  const int l16 = lane & 15;
  const int c = l16 * 8;      // 8 halfs per lane

  f16x2 b1h[4], w2h[4];
  {
    const floatx4 b1a = *(const floatx4*)(b1 + c);
    const floatx4 b1b = *(const floatx4*)(b1 + c + 4);
    const floatx4 w2a = *(const floatx4*)(W2 + c);
    const floatx4 w2b = *(const floatx4*)(W2 + c + 4);
    b1h[0] = f16x2{(_Float16)b1a.x, (_Float16)b1a.y};
    b1h[1] = f16x2{(_Float16)b1a.z, (_Float16)b1a.w};
    b1h[2] = f16x2{(_Float16)b1b.x, (_Float16)b1b.y};
    b1h[3] = f16x2{(_Float16)b1b.z, (_Float16)b1b.w};
    w2h[0] = f16x2{(_Float16)w2a.x, (_Float16)w2a.y};
    w2h[1] = f16x2{(_Float16)w2a.z, (_Float16)w2a.w};
    w2h[2] = f16x2{(_Float16)w2b.x, (_Float16)w2b.y};
    w2h[3] = f16x2{(_Float16)w2b.z, (_Float16)w2b.w};
  }
  const f16x2 z2 = {(_Float16)0.f, (_Float16)0.f};
  const float b2v = b2[0];

  const int e0 = (blockIdx.x * 4 + wid) * 16;

  uint4 rs[4], rt_[4];
#pragma unroll
  for (int j = 0; j < 4; ++j) {
    const int ej = e0 + j * 4 + g;
    const int src = lm[ej];
    const int tgt = lm[NEDGES + ej];
    rs[j]  = *(const uint4*)(P + (size_t)src * 256 + c);
    rt_[j] = *(const uint4*)(P + (size_t)tgt * 256 + 128 + c);
  }
  float lsum = 0.f;
#pragma unroll
  for (int j = 0; j < 4; ++j) {
    float p = 0.f;
    const unsigned su[4] = {rs[j].x, rs[j].y, rs[j].z, rs[j].w};
    const unsigned tu[4] = {rt_[j].x, rt_[j].y, rt_[j].z, rt_[j].w};
#pragma unroll
    for (int h = 0; h < 4; ++h) {
      const f16x2 s = __builtin_bit_cast(f16x2, su[h]);
      const f16x2 tt = __builtin_bit_cast(f16x2, tu[h]);
      const f16x2 a = __builtin_elementwise_max(s + tt + b1h[h], z2);
      p = __builtin_amdgcn_fdot2(a, w2h[h], p, false);
    }
    p += __shfl_xor(p, 8, 64);
    p += __shfl_xor(p, 4, 64);
    p += __shfl_xor(p, 2, 64);
    p += __shfl_xor(p, 1, 64);
    if (l16 == j) {
      const float ev = __expf(p + b2v);
      explog[e0 + j * 4 + g] = ev;
      lsum += ev;
    }
  }

#pragma unroll
  for (int off = 32; off >= 1; off >>= 1) lsum += __shfl_xor(lsum, off, 64);
  __shared__ float wsums[4];
  if (lane == 0) wsums[wid] = lsum;
  __syncthreads();
  if (threadIdx.x == 0)
    partials[blockIdx.x] = wsums[0] + wsums[1] + wsums[2] + wsums[3];
}

// ---------------- Kernel 2.5: reduce partials -> accum (single block) ------
// 15625 = 3906 float4 + 1 scalar. Independent vector loads (16 in flight).
__global__ __launch_bounds__(256) void reduce_kernel(
    const float* __restrict__ partials, float* __restrict__ accum) {
  float s = 0.f;
  for (int i = threadIdx.x; i < 3906; i += 256) {
    const floatx4 v = *(const floatx4*)(partials + i * 4);
    s += (v.x + v.y) + (v.z + v.w);
  }
  if (threadIdx.x == 0) s += partials[15624];
#pragma unroll
  for (int off = 32; off >= 1; off >>= 1) s += __shfl_xor(s, off, 64);
  __shared__ float ws_[4];
  if ((threadIdx.x & 63) == 0) ws_[threadIdx.x >> 6] = s;
  __syncthreads();
  if (threadIdx.x == 0) accum[0] = ws_[0] + ws_[1] + ws_[2] + ws_[3];
}

// ---------------- Kernel 3: normalize ----------------
__global__ __launch_bounds__(256) void norm_kernel(
    const float* __restrict__ explog, const float* __restrict__ sum_accum,
    float* __restrict__ out) {
  const float inv = 1.0f / *sum_accum;
  const int i = (blockIdx.x * 256 + threadIdx.x) * 4;
  if (i < NEDGES) {
    floatx4 v = *(const floatx4*)(explog + i);
    v.x *= inv; v.y *= inv; v.z *= inv; v.w *= inv;
    *(floatx4*)(out + i) = v;
  }
}

extern "C" void kernel_launch(void* const* d_in, const int* in_sizes, int n_in,
                              void* d_out, int out_size, void* d_ws, size_t ws_size,
                              hipStream_t stream) {
  const float* emb = (const float*)d_in[0];
  const int*   lm  = (const int*)d_in[1];   // [2, 1M]: sources then targets
  const float* W1  = (const float*)d_in[2];
  const float* b1  = (const float*)d_in[3];
  const float* W2  = (const float*)d_in[4];
  const float* b2  = (const float*)d_in[5];
  float* out = (float*)d_out;

  char* ws = (char*)d_ws;
  __half* P       = (__half*)ws;                   // 51,200,000 B
  float* accum    = (float*)(ws + 51200000);       // 256 B
  float* explog   = (float*)(ws + 51200256);       // 4,000,000 B
  _Float16* Bf    = (_Float16*)(ws + 55200256);    // 65,536 B
  float* partials = (float*)(ws + 55265792);       // 15625*4 B

  pack_b_kernel<<<16, 256, 0, stream>>>(W1, Bf);
  project_kernel<<<1563, 256, 0, stream>>>(emb, Bf, P);
  edge_kernel<<<NEBLOCKS, 256, 0, stream>>>(P, lm, b1, W2, b2, explog, partials);
  reduce_kernel<<<1, 256, 0, stream>>>(partials, accum);
  norm_kernel<<<977, 256, 0, stream>>>(explog, accum, out);
}